// Round 2
// baseline (201.054 us; speedup 1.0000x reference)
//
#include <hip/hip_runtime.h>
#include <math.h>

#define IN_CH 64
#define OUT_CH 64
#define M1 32
#define M2 32
#define HH 512
#define WW 512

// ---------------- workspace layout (floats) ----------------
// F   : [512][64]   cos(2*pi*k*w/512) in cols 0..31, sin(...) in cols 32..63
// Xw  : [64][512][64]  forward w-DFT: re(ky 0..31) | im(ky 0..31)
// XFr : [32][32][64]   [kx][ky][i]
// XFi : [32][32][64]
// Lr  : [64][32][32]   [o][kx][ky]
// Li  : [64][32][32]
// Z   : [64][512][64]  scaled: re | im
// FT  : [64][512]   transposed table: row j<32 = cos(2pi j w/512), j>=32 = sin
static const size_t OFF_F   = 0;
static const size_t OFF_XW  = 32768;
static const size_t OFF_XFR = OFF_XW  + (size_t)64*512*64;
static const size_t OFF_XFI = OFF_XFR + (size_t)32*32*64;
static const size_t OFF_LR  = OFF_XFI + (size_t)32*32*64;
static const size_t OFF_LI  = OFF_LR  + (size_t)64*32*32;
static const size_t OFF_Z   = OFF_LI  + (size_t)64*32*32;
static const size_t OFF_FT  = OFF_Z   + (size_t)64*512*64;

__global__ void build_table(float* __restrict__ F, float* __restrict__ FT) {
    int idx = blockIdx.x * 256 + threadIdx.x;      // 0..32767
    int w = idx >> 6, j = idx & 63, k = j & 31;
    int m = (k * w) & 511;                          // exact angle reduction
    float ang = (6.283185307179586f / 512.0f) * (float)m;
    float s, c;
    sincosf(ang, &s, &c);
    float v = (j < 32) ? c : s;
    F[idx] = v;
    FT[(size_t)j * 512 + w] = v;
}

// Stage A: Xw[row][j] = sgn_j * sum_w x[row][w] * F[w][j]  (sgn: -1 for sin cols)
// GEMM M=32768 (rows = i*512+h), N=64, K=512. BM=64, BN=64, BK=64.
__global__ __launch_bounds__(256) void stageA(const float* __restrict__ x,
                                              const float* __restrict__ F,
                                              float* __restrict__ Xw) {
    __shared__ float xs[64][65];
    __shared__ float fs[64][64];
    int t  = threadIdx.x;
    int tx = t & 15;          // col group (4 cols)
    int ty = t >> 4;          // row group (4 rows)
    int rowBase = blockIdx.x * 64;

    float acc[4][4];
#pragma unroll
    for (int r = 0; r < 4; ++r)
#pragma unroll
        for (int c = 0; c < 4; ++c) acc[r][c] = 0.f;

    for (int w0 = 0; w0 < 512; w0 += 64) {
        // load x tile 64x64 (rows may cross channels; rows are independent)
#pragma unroll
        for (int p = 0; p < 4; ++p) {
            int rl = (t >> 4) + p * 16;
            int c4 = (t & 15) * 4;
            float4 v = *(const float4*)&x[(size_t)(rowBase + rl) * 512 + w0 + c4];
            xs[rl][c4 + 0] = v.x; xs[rl][c4 + 1] = v.y;
            xs[rl][c4 + 2] = v.z; xs[rl][c4 + 3] = v.w;
        }
        // load F tile 64x64 (contiguous)
#pragma unroll
        for (int p = 0; p < 4; ++p) {
            int flat = p * 1024 + t * 4;
            float4 v = *(const float4*)&F[(size_t)w0 * 64 + flat];
            *(float4*)&fs[flat >> 6][flat & 63] = v;
        }
        __syncthreads();
#pragma unroll 8
        for (int w = 0; w < 64; ++w) {
            float4 f4 = *(const float4*)&fs[w][tx * 4];
#pragma unroll
            for (int r = 0; r < 4; ++r) {
                float xv = xs[ty * 4 + r][w];
                acc[r][0] += xv * f4.x; acc[r][1] += xv * f4.y;
                acc[r][2] += xv * f4.z; acc[r][3] += xv * f4.w;
            }
        }
        __syncthreads();
    }
    float sgn = (tx < 8) ? 1.f : -1.f;
#pragma unroll
    for (int r = 0; r < 4; ++r) {
        float4 v = make_float4(acc[r][0] * sgn, acc[r][1] * sgn,
                               acc[r][2] * sgn, acc[r][3] * sgn);
        *(float4*)&Xw[(size_t)(rowBase + ty * 4 + r) * 64 + tx * 4] = v;
    }
}

// Stage B: XF[i,kx,ky] = sum_h Xw[i,h,ky] * e^{-2pi i kx h/512}
// one wave per (i,ky); lane<32 -> Re for kx=lane, lane>=32 -> Im for kx=lane-32
__global__ __launch_bounds__(256) void stageB(const float* __restrict__ Xw,
                                              const float* __restrict__ F,
                                              float* __restrict__ XFr,
                                              float* __restrict__ XFi) {
    int t = threadIdx.x, wid = t >> 6, lane = t & 63;
    int gw = blockIdx.x * 4 + wid;          // 0..2047
    int i = gw >> 5, ky = gw & 31;
    int j = lane & 31;
    bool isIm = lane >= 32;
    const float* xwb = Xw + (size_t)i * 512 * 64 + ky;
    float acc = 0.f;
    for (int h = 0; h < 512; ++h) {
        float xr = xwb[h * 64];
        float xi = xwb[h * 64 + 32];
        float cv = F[h * 64 + j];
        float sv = F[h * 64 + 32 + j];
        // Re: xr*c + xi*s ; Im: xi*c - xr*s
        float a = isIm ? xi : xr;
        float b = isIm ? -xr : xi;
        acc += a * cv + b * sv;
    }
    if (!isIm) XFr[((size_t)j * 32 + ky) * 64 + i] = acc;
    else       XFi[((size_t)j * 32 + ky) * 64 + i] = acc;
}

// Stage C: L[o,kx,ky] = sum_i XF[i,kx,ky] * (Wr+iWi)[i,o,kx,ky]
// grid: (kx 32) x (ochunk 8); 256 threads: ky=t&31, o_local=t>>5
__global__ __launch_bounds__(256) void stageC(const float* __restrict__ XFr,
                                              const float* __restrict__ XFi,
                                              const float* __restrict__ Wr,
                                              const float* __restrict__ Wi,
                                              float* __restrict__ Lr,
                                              float* __restrict__ Li) {
    __shared__ float sxr[32][65];
    __shared__ float sxi[32][65];
    int t = threadIdx.x;
    int kx = blockIdx.x & 31, oc = blockIdx.x >> 5;
    // stage XF slice [ky][i] (2048 floats each)
    for (int q = 0; q < 8; ++q) {
        int idx = t * 8 + q;                 // 0..2047
        sxr[idx >> 6][idx & 63] = XFr[(size_t)kx * 2048 + idx];
        sxi[idx >> 6][idx & 63] = XFi[(size_t)kx * 2048 + idx];
    }
    __syncthreads();
    int ky = t & 31, ol = t >> 5;
    int o = oc * 8 + ol;
    float lr = 0.f, li = 0.f;
    for (int i = 0; i < 64; ++i) {
        float a = sxr[ky][i];
        float b = sxi[ky][i];
        size_t widx = ((size_t)i * 64 + o) * 1024 + kx * 32 + ky;
        float wrv = Wr[widx];
        float wiv = Wi[widx];
        lr += a * wrv - b * wiv;
        li += a * wiv + b * wrv;
    }
    Lr[((size_t)o * 32 + kx) * 32 + ky] = lr;
    Li[((size_t)o * 32 + kx) * 32 + ky] = li;
}

// Stage D: Z[o,h,ky] = c_ky * sum_kx L[o,kx,ky] * e^{+2pi i kx h/512}
// block: (o, hchunk of 64); 4 waves x 16 h each
__global__ __launch_bounds__(256) void stageD(const float* __restrict__ Lr,
                                              const float* __restrict__ Li,
                                              const float* __restrict__ F,
                                              float* __restrict__ Z) {
    __shared__ float sLr[32][32];
    __shared__ float sLi[32][32];
    int t = threadIdx.x;
    int o = blockIdx.x >> 3, hc = blockIdx.x & 7;
    for (int q = 0; q < 4; ++q) {
        int idx = t + q * 256;               // 0..1023
        sLr[idx >> 5][idx & 31] = Lr[(size_t)o * 1024 + idx];
        sLi[idx >> 5][idx & 31] = Li[(size_t)o * 1024 + idx];
    }
    __syncthreads();
    int lane = t & 63, wid = t >> 6;
    int ky = lane & 31;
    bool isIm = lane >= 32;
    float scale = ((ky == 0) ? 1.0f : 2.0f) * (1.0f / (512.0f * 512.0f));
    for (int hh = 0; hh < 16; ++hh) {
        int h = hc * 64 + wid * 16 + hh;
        float re = 0.f, im = 0.f;
#pragma unroll 8
        for (int kx = 0; kx < 32; ++kx) {
            float a = sLr[kx][ky], b = sLi[kx][ky];
            float cv = F[h * 64 + kx];
            float sv = F[h * 64 + 32 + kx];
            re += a * cv - b * sv;
            im += a * sv + b * cv;
        }
        float val = isIm ? im : re;
        Z[((size_t)o * 512 + h) * 64 + lane] = val * scale;
    }
}

// Stage E: out[o,h,w] = sum_{ky<32} Zr[ky]*cos(2pi ky w/512) - Zi[ky]*sin(...)
// thread = w (512/block); z-row values are block-uniform -> scalar loads (SGPR),
// cw/sw live in 64 VGPRs loaded coalesced from transposed table FT.
__global__ __launch_bounds__(512) void stageE(const float* __restrict__ Z,
                                              const float* __restrict__ FT,
                                              float* __restrict__ out) {
    int t = threadIdx.x;                     // w
    int o = blockIdx.x >> 4, hc = blockIdx.x & 15;
    float cw[32], sw[32];
#pragma unroll
    for (int k = 0; k < 32; ++k) {
        cw[k] = FT[(size_t)k * 512 + t];
        sw[k] = FT[(size_t)(k + 32) * 512 + t];
    }
    const float* zrow = Z + ((size_t)o * 512 + hc * 32) * 64;
    float* orow = out + ((size_t)o * 512 + hc * 32) * 512 + t;
    for (int r = 0; r < 32; ++r) {
        float acc0 = 0.f, acc1 = 0.f;
#pragma unroll
        for (int k = 0; k < 32; ++k) {
            float zr = zrow[r * 64 + k];        // uniform -> s_load
            float zi = zrow[r * 64 + 32 + k];   // uniform -> s_load
            acc0 += zr * cw[k];
            acc1 += zi * sw[k];
        }
        orow[(size_t)r * 512] = acc0 - acc1;
    }
}

extern "C" void kernel_launch(void* const* d_in, const int* in_sizes, int n_in,
                              void* d_out, int out_size, void* d_ws, size_t ws_size,
                              hipStream_t stream) {
    const float* x  = (const float*)d_in[0];
    const float* Wr = (const float*)d_in[1];
    const float* Wi = (const float*)d_in[2];
    float* out = (float*)d_out;
    float* ws  = (float*)d_ws;

    float* F   = ws + OFF_F;
    float* Xw  = ws + OFF_XW;
    float* XFr = ws + OFF_XFR;
    float* XFi = ws + OFF_XFI;
    float* Lr  = ws + OFF_LR;
    float* Li  = ws + OFF_LI;
    float* Z   = ws + OFF_Z;
    float* FT  = ws + OFF_FT;

    build_table<<<128, 256, 0, stream>>>(F, FT);
    stageA<<<512, 256, 0, stream>>>(x, F, Xw);
    stageB<<<512, 256, 0, stream>>>(Xw, F, XFr, XFi);
    stageC<<<256, 256, 0, stream>>>(XFr, XFi, Wr, Wi, Lr, Li);
    stageD<<<512, 256, 0, stream>>>(Lr, Li, F, Z);
    stageE<<<1024, 512, 0, stream>>>(Z, FT, out);
}

// Round 3
// 143.354 us; speedup vs baseline: 1.4025x; 1.4025x over previous
//
#include <hip/hip_runtime.h>
#include <math.h>

#define IN_CH 64
#define OUT_CH 64
#define M1 32
#define M2 32
#define HH 512
#define WW 512

// ---------------- workspace layout (floats) ----------------
// F   : [512][64]   cos(2*pi*k*w/512) in cols 0..31, sin(...) in cols 32..63
// Xw  : [64][512][64]  forward w-DFT: re(ky 0..31) | im(ky 0..31)
// XFr : [32][32][64]   [kx][ky][i]
// XFi : [32][32][64]
// Lr  : [64][32][32]   [o][kx][ky]
// Li  : [64][32][32]
// Z   : [64][512][64]  scaled: re | im
// GT  : [64][512]   row j<32: cos(2pi j w/512); row j>=32: -sin(2pi (j-32) w/512)
static const size_t OFF_F   = 0;
static const size_t OFF_XW  = 32768;
static const size_t OFF_XFR = OFF_XW  + (size_t)64*512*64;
static const size_t OFF_XFI = OFF_XFR + (size_t)32*32*64;
static const size_t OFF_LR  = OFF_XFI + (size_t)32*32*64;
static const size_t OFF_LI  = OFF_LR  + (size_t)64*32*32;
static const size_t OFF_Z   = OFF_LI  + (size_t)64*32*32;
static const size_t OFF_GT  = OFF_Z   + (size_t)64*512*64;

__global__ void build_table(float* __restrict__ F, float* __restrict__ GT) {
    int idx = blockIdx.x * 256 + threadIdx.x;      // 0..32767
    int w = idx >> 6, j = idx & 63, k = j & 31;
    int m = (k * w) & 511;                          // exact angle reduction
    float ang = (6.283185307179586f / 512.0f) * (float)m;
    float s, c;
    sincosf(ang, &s, &c);
    F[idx] = (j < 32) ? c : s;
    GT[(size_t)j * 512 + w] = (j < 32) ? c : -s;
}

// Stage A: Xw[row][j] = sgn_j * sum_w x[row][w] * F[w][j]  (sgn: -1 for sin cols)
// GEMM M=32768 (rows = i*512+h), N=64, K=512. BM=64, BN=64, BK=64.
__global__ __launch_bounds__(256) void stageA(const float* __restrict__ x,
                                              const float* __restrict__ F,
                                              float* __restrict__ Xw) {
    __shared__ float xs[64][65];
    __shared__ float fs[64][64];
    int t  = threadIdx.x;
    int tx = t & 15;          // col group (4 cols)
    int ty = t >> 4;          // row group (4 rows)
    int rowBase = blockIdx.x * 64;

    float acc[4][4];
#pragma unroll
    for (int r = 0; r < 4; ++r)
#pragma unroll
        for (int c = 0; c < 4; ++c) acc[r][c] = 0.f;

    for (int w0 = 0; w0 < 512; w0 += 64) {
        // load x tile 64x64 (rows may cross channels; rows are independent)
#pragma unroll
        for (int p = 0; p < 4; ++p) {
            int rl = (t >> 4) + p * 16;
            int c4 = (t & 15) * 4;
            float4 v = *(const float4*)&x[(size_t)(rowBase + rl) * 512 + w0 + c4];
            xs[rl][c4 + 0] = v.x; xs[rl][c4 + 1] = v.y;
            xs[rl][c4 + 2] = v.z; xs[rl][c4 + 3] = v.w;
        }
        // load F tile 64x64 (contiguous)
#pragma unroll
        for (int p = 0; p < 4; ++p) {
            int flat = p * 1024 + t * 4;
            float4 v = *(const float4*)&F[(size_t)w0 * 64 + flat];
            *(float4*)&fs[flat >> 6][flat & 63] = v;
        }
        __syncthreads();
#pragma unroll 8
        for (int w = 0; w < 64; ++w) {
            float4 f4 = *(const float4*)&fs[w][tx * 4];
#pragma unroll
            for (int r = 0; r < 4; ++r) {
                float xv = xs[ty * 4 + r][w];
                acc[r][0] += xv * f4.x; acc[r][1] += xv * f4.y;
                acc[r][2] += xv * f4.z; acc[r][3] += xv * f4.w;
            }
        }
        __syncthreads();
    }
    float sgn = (tx < 8) ? 1.f : -1.f;
#pragma unroll
    for (int r = 0; r < 4; ++r) {
        float4 v = make_float4(acc[r][0] * sgn, acc[r][1] * sgn,
                               acc[r][2] * sgn, acc[r][3] * sgn);
        *(float4*)&Xw[(size_t)(rowBase + ty * 4 + r) * 64 + tx * 4] = v;
    }
}

// Stage B: XF[i,kx,ky] = sum_h Xw[i,h,ky] * e^{-2pi i kx h/512}
// one wave per (i,ky); lane<32 -> Re for kx=lane, lane>=32 -> Im for kx=lane-32
__global__ __launch_bounds__(256) void stageB(const float* __restrict__ Xw,
                                              const float* __restrict__ F,
                                              float* __restrict__ XFr,
                                              float* __restrict__ XFi) {
    int t = threadIdx.x, wid = t >> 6, lane = t & 63;
    int gw = blockIdx.x * 4 + wid;          // 0..2047
    int i = gw >> 5, ky = gw & 31;
    int j = lane & 31;
    bool isIm = lane >= 32;
    const float* xwb = Xw + (size_t)i * 512 * 64 + ky;
    float acc = 0.f;
    for (int h = 0; h < 512; ++h) {
        float xr = xwb[h * 64];
        float xi = xwb[h * 64 + 32];
        float cv = F[h * 64 + j];
        float sv = F[h * 64 + 32 + j];
        // Re: xr*c + xi*s ; Im: xi*c - xr*s
        float a = isIm ? xi : xr;
        float b = isIm ? -xr : xi;
        acc += a * cv + b * sv;
    }
    if (!isIm) XFr[((size_t)j * 32 + ky) * 64 + i] = acc;
    else       XFi[((size_t)j * 32 + ky) * 64 + i] = acc;
}

// Stage C: L[o,kx,ky] = sum_i XF[i,kx,ky] * (Wr+iWi)[i,o,kx,ky]
// grid: (kx 32) x (ochunk 8); 256 threads: ky=t&31, o_local=t>>5
__global__ __launch_bounds__(256) void stageC(const float* __restrict__ XFr,
                                              const float* __restrict__ XFi,
                                              const float* __restrict__ Wr,
                                              const float* __restrict__ Wi,
                                              float* __restrict__ Lr,
                                              float* __restrict__ Li) {
    __shared__ float sxr[32][65];
    __shared__ float sxi[32][65];
    int t = threadIdx.x;
    int kx = blockIdx.x & 31, oc = blockIdx.x >> 5;
    // stage XF slice [ky][i] (2048 floats each)
    for (int q = 0; q < 8; ++q) {
        int idx = t * 8 + q;                 // 0..2047
        sxr[idx >> 6][idx & 63] = XFr[(size_t)kx * 2048 + idx];
        sxi[idx >> 6][idx & 63] = XFi[(size_t)kx * 2048 + idx];
    }
    __syncthreads();
    int ky = t & 31, ol = t >> 5;
    int o = oc * 8 + ol;
    float lr = 0.f, li = 0.f;
    for (int i = 0; i < 64; ++i) {
        float a = sxr[ky][i];
        float b = sxi[ky][i];
        size_t widx = ((size_t)i * 64 + o) * 1024 + kx * 32 + ky;
        float wrv = Wr[widx];
        float wiv = Wi[widx];
        lr += a * wrv - b * wiv;
        li += a * wiv + b * wrv;
    }
    Lr[((size_t)o * 32 + kx) * 32 + ky] = lr;
    Li[((size_t)o * 32 + kx) * 32 + ky] = li;
}

// Stage D: Z[o,h,ky] = c_ky * sum_kx L[o,kx,ky] * e^{+2pi i kx h/512}
// block: (o, hchunk of 64); 4 waves x 16 h each
__global__ __launch_bounds__(256) void stageD(const float* __restrict__ Lr,
                                              const float* __restrict__ Li,
                                              const float* __restrict__ F,
                                              float* __restrict__ Z) {
    __shared__ float sLr[32][32];
    __shared__ float sLi[32][32];
    int t = threadIdx.x;
    int o = blockIdx.x >> 3, hc = blockIdx.x & 7;
    for (int q = 0; q < 4; ++q) {
        int idx = t + q * 256;               // 0..1023
        sLr[idx >> 5][idx & 31] = Lr[(size_t)o * 1024 + idx];
        sLi[idx >> 5][idx & 31] = Li[(size_t)o * 1024 + idx];
    }
    __syncthreads();
    int lane = t & 63, wid = t >> 6;
    int ky = lane & 31;
    bool isIm = lane >= 32;
    float scale = ((ky == 0) ? 1.0f : 2.0f) * (1.0f / (512.0f * 512.0f));
    for (int hh = 0; hh < 16; ++hh) {
        int h = hc * 64 + wid * 16 + hh;
        float re = 0.f, im = 0.f;
#pragma unroll 8
        for (int kx = 0; kx < 32; ++kx) {
            float a = sLr[kx][ky], b = sLi[kx][ky];
            float cv = F[h * 64 + kx];
            float sv = F[h * 64 + 32 + kx];
            re += a * cv - b * sv;
            im += a * sv + b * cv;
        }
        float val = isIm ? im : re;
        Z[((size_t)o * 512 + h) * 64 + lane] = val * scale;
    }
}

// Stage E as GEMM: out[row][w] = sum_{j<64} Z[row][j] * GT[j][w]
// M=32768 rows=(o*512+h), N=512 (w), K=64. BM=64, BN=64, full K in one tile.
// zt stored transposed [k][row], gs [k][w] -> inner loop = 2x ds_read_b128 / 16 FMA.
__global__ __launch_bounds__(256) void stageE(const float* __restrict__ Z,
                                              const float* __restrict__ GT,
                                              float* __restrict__ out) {
    __shared__ float zt[64][68];   // [k][row], padded for alignment+banks
    __shared__ float gs[64][68];   // [k][w]
    int t = threadIdx.x;
    int rb = blockIdx.x >> 3, cb = blockIdx.x & 7;  // 8 consecutive blocks share Z tile
    int rowBase = rb * 64, w0 = cb * 64;

#pragma unroll
    for (int p = 0; p < 4; ++p) {
        int flat = p * 1024 + t * 4;
        int row = flat >> 6, c4 = flat & 63;
        float4 v = *(const float4*)&Z[(size_t)(rowBase + row) * 64 + c4];
        zt[c4 + 0][row] = v.x; zt[c4 + 1][row] = v.y;
        zt[c4 + 2][row] = v.z; zt[c4 + 3][row] = v.w;
        float4 g = *(const float4*)&GT[(size_t)row * 512 + w0 + c4];
        *(float4*)&gs[row][c4] = g;
    }
    __syncthreads();

    int tx = t & 15, ty = t >> 4;
    float acc[4][4];
#pragma unroll
    for (int r = 0; r < 4; ++r)
#pragma unroll
        for (int c = 0; c < 4; ++c) acc[r][c] = 0.f;

#pragma unroll 8
    for (int k = 0; k < 64; ++k) {
        float4 zv = *(const float4*)&zt[k][ty * 4];
        float4 gv = *(const float4*)&gs[k][tx * 4];
        acc[0][0] += zv.x * gv.x; acc[0][1] += zv.x * gv.y;
        acc[0][2] += zv.x * gv.z; acc[0][3] += zv.x * gv.w;
        acc[1][0] += zv.y * gv.x; acc[1][1] += zv.y * gv.y;
        acc[1][2] += zv.y * gv.z; acc[1][3] += zv.y * gv.w;
        acc[2][0] += zv.z * gv.x; acc[2][1] += zv.z * gv.y;
        acc[2][2] += zv.z * gv.z; acc[2][3] += zv.z * gv.w;
        acc[3][0] += zv.w * gv.x; acc[3][1] += zv.w * gv.y;
        acc[3][2] += zv.w * gv.z; acc[3][3] += zv.w * gv.w;
    }

#pragma unroll
    for (int r = 0; r < 4; ++r) {
        float4 v = make_float4(acc[r][0], acc[r][1], acc[r][2], acc[r][3]);
        *(float4*)&out[(size_t)(rowBase + ty * 4 + r) * 512 + w0 + tx * 4] = v;
    }
}

extern "C" void kernel_launch(void* const* d_in, const int* in_sizes, int n_in,
                              void* d_out, int out_size, void* d_ws, size_t ws_size,
                              hipStream_t stream) {
    const float* x  = (const float*)d_in[0];
    const float* Wr = (const float*)d_in[1];
    const float* Wi = (const float*)d_in[2];
    float* out = (float*)d_out;
    float* ws  = (float*)d_ws;

    float* F   = ws + OFF_F;
    float* Xw  = ws + OFF_XW;
    float* XFr = ws + OFF_XFR;
    float* XFi = ws + OFF_XFI;
    float* Lr  = ws + OFF_LR;
    float* Li  = ws + OFF_LI;
    float* Z   = ws + OFF_Z;
    float* GT  = ws + OFF_GT;

    build_table<<<128, 256, 0, stream>>>(F, GT);
    stageA<<<512, 256, 0, stream>>>(x, F, Xw);
    stageB<<<512, 256, 0, stream>>>(Xw, F, XFr, XFi);
    stageC<<<256, 256, 0, stream>>>(XFr, XFi, Wr, Wi, Lr, Li);
    stageD<<<512, 256, 0, stream>>>(Lr, Li, F, Z);
    stageE<<<4096, 256, 0, stream>>>(Z, GT, out);
}

// Round 4
// 101.657 us; speedup vs baseline: 1.9778x; 1.4102x over previous
//
#include <hip/hip_runtime.h>
#include <math.h>

#define IN_CH 64
#define OUT_CH 64
#define M1 32
#define M2 32
#define HH 512
#define WW 512

// ---------------- workspace layout (floats) ----------------
// F   : [512][64]  cols 0..31 = cos(2pi k idx/512), cols 32..63 = sin(...)
// GT  : [64][512]  row j<32: cos(2pi j t/512); row j>=32: -sin(2pi (j-32) t/512)
// Xw0 : [64][512][64]  partial w-DFT (K-half 0): re(ky 0..31) | im(ky 0..31), sin-sign applied
// Xw1 : same, K-half 1
// XFp : [64 i][8 ht][2 reim][32 kx][32 ky]  partial h-DFT
// Lr  : [64 o][32 kx][32 ky]   (scaled)
// Li  : [64 o][32 kx][32 ky]
// Z   : aliases Xw0  [64 o][512 h][64 j]  (j<32 re-ky, j>=32 im-ky)
static const size_t OFF_F   = 0;
static const size_t OFF_GT  = 32768;
static const size_t OFF_XW0 = 65536;
static const size_t OFF_XW1 = OFF_XW0 + (size_t)64*512*64;
static const size_t OFF_XFP = OFF_XW1 + (size_t)64*512*64;
static const size_t OFF_LR  = OFF_XFP + (size_t)64*8*2*32*32;
static const size_t OFF_LI  = OFF_LR  + (size_t)64*32*32;
static const size_t OFF_Z   = OFF_XW0;   // alias: Xw0 dead after stageB

__global__ void build_table(float* __restrict__ F, float* __restrict__ GT) {
    int idx = blockIdx.x * 256 + threadIdx.x;      // 0..32767
    int w = idx >> 6, j = idx & 63, k = j & 31;
    int m = (k * w) & 511;                          // exact angle reduction
    float ang = (6.283185307179586f / 512.0f) * (float)m;
    float s, c;
    sincosf(ang, &s, &c);
    F[idx] = (j < 32) ? c : s;
    GT[(size_t)j * 512 + w] = (j < 32) ? c : -s;
}

// Stage A: Xw[row][j] = sgn_j * sum_w x[row][w] * F[w][j], K-split into 2 halves.
// grid 1024: rb = bid>>1 (row tile of 64), kh = bid&1 (k-half of 256).
__global__ __launch_bounds__(256) void stageA(const float* __restrict__ x,
                                              const float* __restrict__ F,
                                              float* __restrict__ Xw0,
                                              float* __restrict__ Xw1) {
    __shared__ float xs[64][68];
    __shared__ float fs[64][64];
    int t  = threadIdx.x;
    int tx = t & 15;
    int ty = t >> 4;
    int rb = blockIdx.x >> 1, kh = blockIdx.x & 1;
    int rowBase = rb * 64;
    int kbase = kh * 256;

    float acc[4][4];
#pragma unroll
    for (int r = 0; r < 4; ++r)
#pragma unroll
        for (int c = 0; c < 4; ++c) acc[r][c] = 0.f;

    for (int tt = 0; tt < 4; ++tt) {
        int w0 = kbase + tt * 64;
#pragma unroll
        for (int p = 0; p < 4; ++p) {
            int rl = (t >> 4) + p * 16;
            int c4 = (t & 15) * 4;
            float4 v = *(const float4*)&x[(size_t)(rowBase + rl) * 512 + w0 + c4];
            *(float4*)&xs[rl][c4] = v;
            int flat = p * 1024 + t * 4;
            float4 f = *(const float4*)&F[(size_t)w0 * 64 + flat];
            *(float4*)&fs[flat >> 6][flat & 63] = f;
        }
        __syncthreads();
#pragma unroll 4
        for (int k0 = 0; k0 < 64; k0 += 4) {
            float4 xv[4], fv[4];
#pragma unroll
            for (int r = 0; r < 4; ++r) xv[r] = *(const float4*)&xs[ty * 4 + r][k0];
#pragma unroll
            for (int kk = 0; kk < 4; ++kk) fv[kk] = *(const float4*)&fs[k0 + kk][tx * 4];
#pragma unroll
            for (int kk = 0; kk < 4; ++kk) {
#pragma unroll
                for (int r = 0; r < 4; ++r) {
                    float xk = (kk == 0) ? xv[r].x : (kk == 1) ? xv[r].y : (kk == 2) ? xv[r].z : xv[r].w;
                    acc[r][0] = __builtin_fmaf(xk, fv[kk].x, acc[r][0]);
                    acc[r][1] = __builtin_fmaf(xk, fv[kk].y, acc[r][1]);
                    acc[r][2] = __builtin_fmaf(xk, fv[kk].z, acc[r][2]);
                    acc[r][3] = __builtin_fmaf(xk, fv[kk].w, acc[r][3]);
                }
            }
        }
        __syncthreads();
    }
    float sgn = (tx < 8) ? 1.f : -1.f;
    float* Xwp = kh ? Xw1 : Xw0;
#pragma unroll
    for (int r = 0; r < 4; ++r) {
        float4 v = make_float4(acc[r][0] * sgn, acc[r][1] * sgn,
                               acc[r][2] * sgn, acc[r][3] * sgn);
        *(float4*)&Xwp[(size_t)(rowBase + ty * 4 + r) * 64 + tx * 4] = v;
    }
}

// Stage B: partial h-DFT. grid 512: i = bid>>3, ht = bid&7 (h-tile of 64).
// XFp[i][ht][re/im][kx][ky] = sum_{h in tile} Xw[i,h,ky] * e^{-2pi i kx h/512}
__global__ __launch_bounds__(256) void stageB(const float* __restrict__ Xw0,
                                              const float* __restrict__ Xw1,
                                              const float* __restrict__ GT,
                                              float* __restrict__ XFp) {
    __shared__ float xw[64][68];   // [hh][j]
    __shared__ float gt[64][68];   // [j][hh]  (j<32 cos, j>=32 -sin)
    int t = threadIdx.x;
    int i = blockIdx.x >> 3, ht = blockIdx.x & 7;
    int h0 = ht * 64;

#pragma unroll
    for (int p = 0; p < 4; ++p) {
        int flat = p * 1024 + t * 4;
        int hh = flat >> 6, c4 = flat & 63;
        float4 a = *(const float4*)&Xw0[((size_t)i * 512 + h0 + hh) * 64 + c4];
        float4 b = *(const float4*)&Xw1[((size_t)i * 512 + h0 + hh) * 64 + c4];
        float4 s = make_float4(a.x + b.x, a.y + b.y, a.z + b.z, a.w + b.w);
        *(float4*)&xw[hh][c4] = s;
        int j = flat >> 6, hc = flat & 63;
        float4 g = *(const float4*)&GT[(size_t)j * 512 + h0 + hc];
        *(float4*)&gt[j][hc] = g;
    }
    __syncthreads();

    int kx = t >> 3, kg = t & 7;   // ky = kg*4..kg*4+3
    float rr[4] = {0.f, 0.f, 0.f, 0.f};
    float ii[4] = {0.f, 0.f, 0.f, 0.f};
#pragma unroll 4
    for (int hh = 0; hh < 64; ++hh) {
        float cv = gt[kx][hh];
        float sv = gt[kx + 32][hh];          // = -sin
        float4 xr = *(const float4*)&xw[hh][kg * 4];
        float4 xi = *(const float4*)&xw[hh][32 + kg * 4];
        // Re = xr*c + xi*s = xr*cv - xi*sv ; Im = xi*c - xr*s = xi*cv + xr*sv
        rr[0] = __builtin_fmaf(xr.x, cv, rr[0]); rr[0] = __builtin_fmaf(xi.x, -sv, rr[0]);
        rr[1] = __builtin_fmaf(xr.y, cv, rr[1]); rr[1] = __builtin_fmaf(xi.y, -sv, rr[1]);
        rr[2] = __builtin_fmaf(xr.z, cv, rr[2]); rr[2] = __builtin_fmaf(xi.z, -sv, rr[2]);
        rr[3] = __builtin_fmaf(xr.w, cv, rr[3]); rr[3] = __builtin_fmaf(xi.w, -sv, rr[3]);
        ii[0] = __builtin_fmaf(xi.x, cv, ii[0]); ii[0] = __builtin_fmaf(xr.x, sv, ii[0]);
        ii[1] = __builtin_fmaf(xi.y, cv, ii[1]); ii[1] = __builtin_fmaf(xr.y, sv, ii[1]);
        ii[2] = __builtin_fmaf(xi.z, cv, ii[2]); ii[2] = __builtin_fmaf(xr.z, sv, ii[2]);
        ii[3] = __builtin_fmaf(xi.w, cv, ii[3]); ii[3] = __builtin_fmaf(xr.w, sv, ii[3]);
    }
    size_t base = ((size_t)i * 8 + ht) * 2048;
    *(float4*)&XFp[base + t * 4]        = make_float4(rr[0], rr[1], rr[2], rr[3]);
    *(float4*)&XFp[base + 1024 + t * 4] = make_float4(ii[0], ii[1], ii[2], ii[3]);
}

// Stage C: L[o,kx,ky] = scale(ky) * sum_i XF[i,kx,ky] * (Wr+iWi)[i,o,kx,ky]
// grid 256: kx = bid&31, oc = bid>>5. ht-sum folded into the load.
__global__ __launch_bounds__(256) void stageC(const float* __restrict__ XFp,
                                              const float* __restrict__ Wr,
                                              const float* __restrict__ Wi,
                                              float* __restrict__ Lr,
                                              float* __restrict__ Li) {
    __shared__ float sxr[32][65];   // [ky][i]
    __shared__ float sxi[32][65];
    int t = threadIdx.x;
    int kx = blockIdx.x & 31, oc = blockIdx.x >> 5;
#pragma unroll
    for (int q = 0; q < 8; ++q) {
        int idx = q * 256 + t;               // 0..2047 = i*32+ky
        int i = idx >> 5, ky = idx & 31;
        float sr = 0.f, si = 0.f;
#pragma unroll
        for (int ht = 0; ht < 8; ++ht) {
            size_t base = ((size_t)i * 8 + ht) * 2048 + kx * 32 + ky;
            sr += XFp[base];
            si += XFp[base + 1024];
        }
        sxr[ky][i] = sr;
        sxi[ky][i] = si;
    }
    __syncthreads();
    int ky = t & 31, ol = t >> 5;
    int o = oc * 8 + ol;
    float lr = 0.f, li = 0.f;
    for (int i = 0; i < 64; ++i) {
        float a = sxr[ky][i];
        float b = sxi[ky][i];
        size_t widx = ((size_t)i * 64 + o) * 1024 + kx * 32 + ky;
        float wrv = Wr[widx];
        float wiv = Wi[widx];
        lr += a * wrv - b * wiv;
        li += a * wiv + b * wrv;
    }
    float sc = ((ky == 0) ? 1.0f : 2.0f) * (1.0f / 262144.0f);
    Lr[((size_t)o * 32 + kx) * 32 + ky] = lr * sc;
    Li[((size_t)o * 32 + kx) * 32 + ky] = li * sc;
}

// Stage D as GEMM: Z[o][h][j] = sum_m F[h][m] * G_o[m][j]
// G_o[m][j]: j<32: (m<32 ? Lr[m][j] : -Li[m-32][j]) ; j>=32: (m<32 ? Li[m][j-32] : Lr[m-32][j-32])
// grid 512: o = bid>>3, ht = bid&7 (h-tile of 64). Scale already folded into L.
__global__ __launch_bounds__(256) void stageD(const float* __restrict__ Lr,
                                              const float* __restrict__ Li,
                                              const float* __restrict__ F,
                                              float* __restrict__ Z) {
    __shared__ float fsD[64][68];   // [hh][m]
    __shared__ float G[64][68];     // [m][j]
    int t = threadIdx.x;
    int o = blockIdx.x >> 3, ht = blockIdx.x & 7;
    int h0 = ht * 64;

#pragma unroll
    for (int p = 0; p < 4; ++p) {
        int flat = p * 1024 + t * 4;
        int hh = flat >> 6, c4 = flat & 63;
        float4 f = *(const float4*)&F[(size_t)(h0 + hh) * 64 + c4];
        *(float4*)&fsD[hh][c4] = f;
    }
#pragma unroll
    for (int q = 0; q < 16; ++q) {
        int idx = q * 256 + t;               // 0..4095 = m*64+j
        int m = idx >> 6, j = idx & 63;
        int ky = j & 31, kxm = m & 31;
        size_t base = (size_t)o * 1024 + kxm * 32 + ky;
        float v;
        if (m < 32) v = (j < 32) ? Lr[base] : Li[base];
        else        v = (j < 32) ? -Li[base] : Lr[base];
        G[m][j] = v;
    }
    __syncthreads();

    int tx = t & 15, ty = t >> 4;
    float acc[4][4];
#pragma unroll
    for (int r = 0; r < 4; ++r)
#pragma unroll
        for (int c = 0; c < 4; ++c) acc[r][c] = 0.f;

#pragma unroll 4
    for (int m0 = 0; m0 < 64; m0 += 4) {
        float4 xv[4], gv[4];
#pragma unroll
        for (int r = 0; r < 4; ++r) xv[r] = *(const float4*)&fsD[ty * 4 + r][m0];
#pragma unroll
        for (int kk = 0; kk < 4; ++kk) gv[kk] = *(const float4*)&G[m0 + kk][tx * 4];
#pragma unroll
        for (int kk = 0; kk < 4; ++kk) {
#pragma unroll
            for (int r = 0; r < 4; ++r) {
                float xk = (kk == 0) ? xv[r].x : (kk == 1) ? xv[r].y : (kk == 2) ? xv[r].z : xv[r].w;
                acc[r][0] = __builtin_fmaf(xk, gv[kk].x, acc[r][0]);
                acc[r][1] = __builtin_fmaf(xk, gv[kk].y, acc[r][1]);
                acc[r][2] = __builtin_fmaf(xk, gv[kk].z, acc[r][2]);
                acc[r][3] = __builtin_fmaf(xk, gv[kk].w, acc[r][3]);
            }
        }
    }
#pragma unroll
    for (int r = 0; r < 4; ++r) {
        float4 v = make_float4(acc[r][0], acc[r][1], acc[r][2], acc[r][3]);
        *(float4*)&Z[((size_t)o * 512 + h0 + ty * 4 + r) * 64 + tx * 4] = v;
    }
}

// Stage E as GEMM: out[row][w] = sum_{j<64} Z[row][j] * GT[j][w]
__global__ __launch_bounds__(256) void stageE(const float* __restrict__ Z,
                                              const float* __restrict__ GT,
                                              float* __restrict__ out) {
    __shared__ float zt[64][68];   // [k][row]
    __shared__ float gs[64][68];   // [k][w]
    int t = threadIdx.x;
    int rb = blockIdx.x >> 3, cb = blockIdx.x & 7;
    int rowBase = rb * 64, w0 = cb * 64;

#pragma unroll
    for (int p = 0; p < 4; ++p) {
        int flat = p * 1024 + t * 4;
        int row = flat >> 6, c4 = flat & 63;
        float4 v = *(const float4*)&Z[(size_t)(rowBase + row) * 64 + c4];
        zt[c4 + 0][row] = v.x; zt[c4 + 1][row] = v.y;
        zt[c4 + 2][row] = v.z; zt[c4 + 3][row] = v.w;
        float4 g = *(const float4*)&GT[(size_t)row * 512 + w0 + c4];
        *(float4*)&gs[row][c4] = g;
    }
    __syncthreads();

    int tx = t & 15, ty = t >> 4;
    float acc[4][4];
#pragma unroll
    for (int r = 0; r < 4; ++r)
#pragma unroll
        for (int c = 0; c < 4; ++c) acc[r][c] = 0.f;

#pragma unroll 8
    for (int k = 0; k < 64; ++k) {
        float4 zv = *(const float4*)&zt[k][ty * 4];
        float4 gv = *(const float4*)&gs[k][tx * 4];
        acc[0][0] += zv.x * gv.x; acc[0][1] += zv.x * gv.y;
        acc[0][2] += zv.x * gv.z; acc[0][3] += zv.x * gv.w;
        acc[1][0] += zv.y * gv.x; acc[1][1] += zv.y * gv.y;
        acc[1][2] += zv.y * gv.z; acc[1][3] += zv.y * gv.w;
        acc[2][0] += zv.z * gv.x; acc[2][1] += zv.z * gv.y;
        acc[2][2] += zv.z * gv.z; acc[2][3] += zv.z * gv.w;
        acc[3][0] += zv.w * gv.x; acc[3][1] += zv.w * gv.y;
        acc[3][2] += zv.w * gv.z; acc[3][3] += zv.w * gv.w;
    }

#pragma unroll
    for (int r = 0; r < 4; ++r) {
        float4 v = make_float4(acc[r][0], acc[r][1], acc[r][2], acc[r][3]);
        *(float4*)&out[(size_t)(rowBase + ty * 4 + r) * 512 + w0 + tx * 4] = v;
    }
}

extern "C" void kernel_launch(void* const* d_in, const int* in_sizes, int n_in,
                              void* d_out, int out_size, void* d_ws, size_t ws_size,
                              hipStream_t stream) {
    const float* x  = (const float*)d_in[0];
    const float* Wr = (const float*)d_in[1];
    const float* Wi = (const float*)d_in[2];
    float* out = (float*)d_out;
    float* ws  = (float*)d_ws;

    float* F   = ws + OFF_F;
    float* GT  = ws + OFF_GT;
    float* Xw0 = ws + OFF_XW0;
    float* Xw1 = ws + OFF_XW1;
    float* XFp = ws + OFF_XFP;
    float* Lr  = ws + OFF_LR;
    float* Li  = ws + OFF_LI;
    float* Z   = ws + OFF_Z;

    build_table<<<128, 256, 0, stream>>>(F, GT);
    stageA<<<1024, 256, 0, stream>>>(x, F, Xw0, Xw1);
    stageB<<<512, 256, 0, stream>>>(Xw0, Xw1, GT, XFp);
    stageC<<<256, 256, 0, stream>>>(XFp, Wr, Wi, Lr, Li);
    stageD<<<512, 256, 0, stream>>>(Lr, Li, F, Z);
    stageE<<<4096, 256, 0, stream>>>(Z, GT, out);
}